// Round 3
// baseline (340.944 us; speedup 1.0000x reference)
//
#include <hip/hip_runtime.h>
#include <hip/hip_bf16.h>

#define K_DIM 4096
#define N_DIM 4096
#define R_DIM 16
#define SCALING_F 2.0f

#define BM 256
#define BN 256
#define BK 64   // bf16 elems per K-tile; 128 bytes per LDS row

typedef __attribute__((ext_vector_type(8))) short bf16x8;
typedef __attribute__((ext_vector_type(16))) float f32x16;

__device__ __forceinline__ ushort f2bf(float f) {
  union { float f; unsigned u; } v; v.f = f;
  unsigned u = v.u;
  u += 0x7FFF + ((u >> 16) & 1);   // round-to-nearest-even
  return (ushort)(u >> 16);
}

// ---- fused pre-pass: blocks [0,4096) fold W; blocks [4096,6144) convert x ----
__global__ __launch_bounds__(256) void prepass_kernel(
    const float* __restrict__ x, ushort* __restrict__ xb,
    const float* __restrict__ W, const float* __restrict__ A,
    const float* __restrict__ Bl, ushort* __restrict__ wb, long n4) {
  if (blockIdx.x < N_DIM) {
    // W_eff = W + 2.0 * (lora_B @ lora_A), cast bf16
    int o = blockIdx.x;
    float breg[R_DIM];
#pragma unroll
    for (int r = 0; r < R_DIM; ++r) breg[r] = Bl[o * R_DIM + r] * SCALING_F;
    for (int d0 = threadIdx.x * 4; d0 < K_DIM; d0 += blockDim.x * 4) {
      float4 w = *(const float4*)(W + (size_t)o * K_DIM + d0);
      float a0 = w.x, a1 = w.y, a2 = w.z, a3 = w.w;
#pragma unroll
      for (int r = 0; r < R_DIM; ++r) {
        float4 a = *(const float4*)(A + (size_t)r * K_DIM + d0);
        a0 += breg[r] * a.x; a1 += breg[r] * a.y;
        a2 += breg[r] * a.z; a3 += breg[r] * a.w;
      }
      ushort4 ob;
      ob.x = f2bf(a0); ob.y = f2bf(a1); ob.z = f2bf(a2); ob.w = f2bf(a3);
      *(ushort4*)(wb + (size_t)o * K_DIM + d0) = ob;
    }
  } else {
    // x fp32 -> bf16
    long i = (long)(blockIdx.x - N_DIM) * blockDim.x + threadIdx.x;
    long stride = 2048L * blockDim.x;
    for (; i < n4; i += stride) {
      long idx = i * 4;
      float4 v = *(const float4*)(x + idx);
      ushort4 o;
      o.x = f2bf(v.x); o.y = f2bf(v.y); o.z = f2bf(v.z); o.w = f2bf(v.w);
      *(ushort4*)(xb + idx) = o;
    }
  }
}

// ============================ 256x256 8-phase GEMM ============================
// 8 waves (2M x 4N), per-wave 128x64 output as 4x2 tiles of 32x32 MFMA.
// LDS 128 KiB: A buf0 [0,32K) buf1 [32K,64K); B buf0 [64K,96K) buf1 [96K,128K).
// Row-major 256 rows x 128 B per buffer, XOR-swizzled 16B chunks:
//   LDS[row][c] holds G[row][c ^ (row&7)]  (3-bit involution on chunk index).
// Staged via inverse-swizzled GLOBAL source + linear global_load_lds dest.
// Stage/wait ledger identical to r2 (verified race-free, vmcnt(6) at ph4/ph8).

#define RS 8192L  // global row stride bytes (K_DIM * 2)

#define GLOAD(SRC, LOFF)                                                    \
  __builtin_amdgcn_global_load_lds(                                         \
      (const __attribute__((address_space(1))) void*)(SRC),                 \
      (__attribute__((address_space(3))) void*)(smem + (LOFF)), 16, 0, 0)

#define LDSA(BUF) ((BUF) * 32768)
#define LDSB(BUF) (65536 + (BUF) * 32768)

#define ST_A_EVEN(T, BUF) do {                                              \
    GLOAD(aS + (size_t)(T) * 128,            LDSA(BUF) + ldsDst);           \
    GLOAD(aS + (size_t)(T) * 128 + 128 * RS, LDSA(BUF) + 16384 + ldsDst); } while (0)
#define ST_A_ODD(T, BUF) do {                                               \
    GLOAD(aS + (size_t)(T) * 128 + 64 * RS,  LDSA(BUF) + 8192 + ldsDst);    \
    GLOAD(aS + (size_t)(T) * 128 + 192 * RS, LDSA(BUF) + 24576 + ldsDst); } while (0)
#define ST_B_H0(T, BUF) do {                                                \
    GLOAD(bS + (size_t)(T) * 128,            LDSB(BUF) + ldsDst);           \
    GLOAD(bS + (size_t)(T) * 128 + 64 * RS,  LDSB(BUF) + 8192 + ldsDst); } while (0)
#define ST_B_H1(T, BUF) do {                                                \
    GLOAD(bS + (size_t)(T) * 128 + 128 * RS, LDSB(BUF) + 16384 + ldsDst);   \
    GLOAD(bS + (size_t)(T) * 128 + 192 * RS, LDSB(BUF) + 24576 + ldsDst); } while (0)

// fragment reads: MI in [0,4) (32-row A tiles), NI in [0,2) (32-col B tiles),
// KS names one of the 4 K=16 slices via precomputed swizzled byte cols cs0..cs3
#define LDAx(MI, KS, BUF) (*(const bf16x8*)(smem + LDSA(BUF) + aRd + (MI) * 4096 + cs##KS))
#define LDBx(NI, KS, BUF) (*(const bf16x8*)(smem + LDSB(BUF) + bRd + (NI) * 4096 + cs##KS))

#define RDB_ALL(BUF) do {                                                   \
    bfr[0][0] = LDBx(0, 0, BUF); bfr[0][1] = LDBx(0, 1, BUF);               \
    bfr[0][2] = LDBx(0, 2, BUF); bfr[0][3] = LDBx(0, 3, BUF);               \
    bfr[1][0] = LDBx(1, 0, BUF); bfr[1][1] = LDBx(1, 1, BUF);               \
    bfr[1][2] = LDBx(1, 2, BUF); bfr[1][3] = LDBx(1, 3, BUF); } while (0)

#define RDA(MB, K0, K1, BUF) do {                                           \
    afr[0][0] = LDAx(MB, K0, BUF);       afr[0][1] = LDAx(MB, K1, BUF);     \
    afr[1][0] = LDAx((MB) + 1, K0, BUF); afr[1][1] = LDAx((MB) + 1, K1, BUF); } while (0)

#define MFMA8(MB, KH) do {                                                  \
    _Pragma("unroll") for (int mm = 0; mm < 2; ++mm)                        \
      _Pragma("unroll") for (int nn = 0; nn < 2; ++nn)                      \
        _Pragma("unroll") for (int kk = 0; kk < 2; ++kk)                    \
          acc[(MB) + mm][nn] = __builtin_amdgcn_mfma_f32_32x32x16_bf16(     \
              afr[mm][kk], bfr[nn][2 * (KH) + kk], acc[(MB) + mm][nn], 0, 0, 0); } while (0)

#define PH_MFMA(MB, KH) do {                                                \
    __builtin_amdgcn_s_barrier();                                           \
    asm volatile("s_waitcnt lgkmcnt(0)" ::: "memory");                      \
    __builtin_amdgcn_s_setprio(1);                                          \
    MFMA8(MB, KH);                                                          \
    __builtin_amdgcn_s_setprio(0); } while (0)

__global__ __launch_bounds__(512, 2) void gemm_lora_kernel(
    const ushort* __restrict__ Ab, const ushort* __restrict__ Bb,
    const float* __restrict__ bias, float* __restrict__ C) {
  __shared__ char smem[131072];

  const int tid = threadIdx.x;
  const int wave = tid >> 6, lane = tid & 63;
  const int wm = wave >> 2, wn = wave & 3;
  const int r31 = lane & 31, hi = lane >> 5;

  // XCD-aware mapping: XCD x owns bm in [4x,4x+4); bn sweeps. grid=512 (%8==0).
  const int bid = blockIdx.x;
  const int bm = ((bid & 7) << 2) + ((bid >> 3) & 3);
  const int bn = bid >> 5;

  // staging source (inverse-swizzled global addresses, 16B chunks)
  const int trow = tid >> 3;                                // 0..63
  const int tswz = ((tid & 7) << 4) ^ ((trow & 7) << 4);    // chunk permute in-row
  const char* aS = (const char*)Ab + (size_t)(bm * BM + trow) * RS + tswz;
  const char* bS = (const char*)Bb + (size_t)(bn * BN + trow) * RS + tswz;
  const int ldsDst = tid << 4;

  // swizzled ds_read byte columns for the 4 K=16 slices
  const int hi16 = hi << 4;
  const int swz  = (lane & 7) << 4;
  const int cs0 = (0  + hi16) ^ swz;
  const int cs1 = (32 + hi16) ^ swz;
  const int cs2 = (64 + hi16) ^ swz;
  const int cs3 = (96 + hi16) ^ swz;
  const int aRd = (wm * 128 + r31) * 128;
  const int bRd = (wn * 64 + r31) * 128;

  f32x16 acc[4][2];
#pragma unroll
  for (int m = 0; m < 4; ++m)
#pragma unroll
    for (int n = 0; n < 2; ++n)
#pragma unroll
      for (int v = 0; v < 16; ++v) acc[m][n][v] = 0.f;
  bf16x8 afr[2][2], bfr[2][4];

  // prologue: tile0 -> buf0 (B0,B1,Ae,Ao); tile1 -> buf1 (B0,B1,Ae). 14 loads.
  ST_B_H0(0, 0); ST_B_H1(0, 0); ST_A_EVEN(0, 0); ST_A_ODD(0, 0);
  ST_B_H0(1, 1); ST_B_H1(1, 1); ST_A_EVEN(1, 1);
  asm volatile("s_waitcnt vmcnt(6)" ::: "memory");  // tile0 fully landed
  __builtin_amdgcn_s_barrier();

  const int NIT = K_DIM / (2 * BK);  // 32
#pragma unroll 1
  for (int i = 0; i < NIT; ++i) {
    const int t1 = 2 * i + 1, t2 = 2 * i + 2, t3 = 2 * i + 3;
    const bool last = (i == NIT - 1);

    // ---- phase 1: buf0, acc rows 0-1, K-slices 0-1 (+ all 8 B frags) ----
    RDB_ALL(0);
    RDA(0, 0, 1, 0);
    ST_A_ODD(t1, 1);
    asm volatile("s_waitcnt lgkmcnt(8)" ::: "memory");
    PH_MFMA(0, 0);
    __builtin_amdgcn_s_barrier();

    // ---- phase 2: buf0, acc rows 0-1, K-slices 2-3 ----
    RDA(0, 2, 3, 0);
    if (!last) ST_B_H0(t2, 0);
    PH_MFMA(0, 1);
    __builtin_amdgcn_s_barrier();

    // ---- phase 3: buf0, acc rows 2-3, K-slices 0-1 ----
    RDA(2, 0, 1, 0);
    if (!last) ST_B_H1(t2, 0);
    PH_MFMA(2, 0);
    __builtin_amdgcn_s_barrier();

    // ---- phase 4: buf0, acc rows 2-3, K-slices 2-3 ; K-tile wait ----
    RDA(2, 2, 3, 0);
    if (!last) ST_A_EVEN(t2, 0);
    PH_MFMA(2, 1);
    if (last) asm volatile("s_waitcnt vmcnt(0)" ::: "memory");
    else      asm volatile("s_waitcnt vmcnt(6)" ::: "memory");
    __builtin_amdgcn_s_barrier();

    // ---- phase 5: buf1, acc rows 0-1, K-slices 0-1 (+ all 8 B frags) ----
    RDB_ALL(1);
    RDA(0, 0, 1, 1);
    if (!last) ST_A_ODD(t2, 0);
    asm volatile("s_waitcnt lgkmcnt(8)" ::: "memory");
    PH_MFMA(0, 0);
    __builtin_amdgcn_s_barrier();

    // ---- phase 6: buf1, acc rows 0-1, K-slices 2-3 ----
    RDA(0, 2, 3, 1);
    if (!last) ST_B_H0(t3, 1);
    PH_MFMA(0, 1);
    __builtin_amdgcn_s_barrier();

    // ---- phase 7: buf1, acc rows 2-3, K-slices 0-1 ----
    RDA(2, 0, 1, 1);
    if (!last) ST_B_H1(t3, 1);
    PH_MFMA(2, 0);
    __builtin_amdgcn_s_barrier();

    // ---- phase 8: buf1, acc rows 2-3, K-slices 2-3 ; K-tile wait ----
    RDA(2, 2, 3, 1);
    if (!last) ST_A_EVEN(t3, 1);
    PH_MFMA(2, 1);
    if (!last) {
      asm volatile("s_waitcnt vmcnt(6)" ::: "memory");
      __builtin_amdgcn_s_barrier();
    }
  }

  // epilogue: 32x32 C/D layout col=lane&31, row=(reg&3)+8*(reg>>2)+4*(lane>>5)
  // [m74/m101 HW-verified]
  const int ccol0 = bn * BN + wn * 64 + r31;
  const float bv0 = bias[ccol0];
  const float bv1 = bias[ccol0 + 32];
  const int crow0 = bm * BM + wm * 128 + hi * 4;
#pragma unroll
  for (int mi = 0; mi < 4; ++mi)
#pragma unroll
    for (int v = 0; v < 16; ++v) {
      int row = crow0 + mi * 32 + (v & 3) + 8 * (v >> 2);
      C[(size_t)row * N_DIM + ccol0]      = acc[mi][0][v] + bv0;
      C[(size_t)row * N_DIM + ccol0 + 32] = acc[mi][1][v] + bv1;
    }
}

extern "C" void kernel_launch(void* const* d_in, const int* in_sizes, int n_in,
                              void* d_out, int out_size, void* d_ws, size_t ws_size,
                              hipStream_t stream) {
  const float* x  = (const float*)d_in[0];   // [M, K]
  const float* W  = (const float*)d_in[1];   // [N, K]
  const float* b  = (const float*)d_in[2];   // [N]
  const float* lA = (const float*)d_in[3];   // [R, K]
  const float* lB = (const float*)d_in[4];   // [N, R]
  float* out = (float*)d_out;                // [M, N]

  const int M = in_sizes[0] / K_DIM;  // 8192

  ushort* xb = (ushort*)d_ws;                 // 64 MB
  ushort* wb = xb + (size_t)M * K_DIM;        // 32 MB

  long n4 = (long)M * K_DIM / 4;
  prepass_kernel<<<N_DIM + 2048, 256, 0, stream>>>(x, xb, W, lA, lB, wb, n4);
  gemm_lora_kernel<<<(M / BM) * (N_DIM / BN), 512, 0, stream>>>(xb, wb, b, out);
}